// Round 5
// baseline (83.664 us; speedup 1.0000x reference)
//
#include <hip/hip_runtime.h>

#define NBOX 8192

// -------------------------------------------------- edge (+fused prep) ------
// Lower-triangular (incl. diagonal) 128x128 tiles over raw inputs.
// Each block recomputes clip + sort-key in-register. Diagonal blocks persist
// keys/validb/cxcywh; bj==0 blocks zero rank/done/out.
// For each overlapping pair, direction by key compare: edge=(loser<<16)|winner.
__global__ __launch_bounds__(256)
void edge_kernel(const float4* __restrict__ boxes,
                 const float* __restrict__ scores,
                 const int* __restrict__ ph, const int* __restrict__ pw,
                 unsigned long long* __restrict__ keys_g,
                 unsigned char* __restrict__ validb_g,
                 float4* __restrict__ cxcywh_g,
                 float4* __restrict__ out, int npro,
                 int* __restrict__ rank_g, int* __restrict__ done_g,
                 unsigned int* __restrict__ edges, int* __restrict__ counter,
                 int ecap) {
#pragma clang fp contract(off)
    __shared__ float4 tj[128];
    __shared__ float  ta[128];
    __shared__ unsigned long long tk[128];
    int b = blockIdx.x;
    int bi = (int)((sqrtf(8.0f * (float)b + 1.0f) - 1.0f) * 0.5f);
    while ((bi + 1) * (bi + 2) / 2 <= b) ++bi;
    while (bi * (bi + 1) / 2 > b) --bi;
    int bj = b - bi * (bi + 1) / 2;
    int t = threadIdx.x;
    int ib = bi * 128, jb = bj * 128;
    float xmax = (float)(*pw - 1);
    float ymax = (float)(*ph - 1);

    if (t < 128) {
        int j = jb + t;
        float4 bx = boxes[j];
        float hw = 0.5f * bx.z, hh = 0.5f * bx.w;
        float x1 = fminf(fmaxf(bx.x - hw, 0.0f), xmax);
        float x2 = fminf(fmaxf(bx.x + hw, 0.0f), xmax);
        float y1 = fminf(fmaxf(bx.y - hh, 0.0f), ymax);
        float y2 = fminf(fmaxf(bx.y + hh, 0.0f), ymax);
        float cw = x2 - x1, ch = y2 - y1;
        bool valid = (cw > 0.0f) && (ch > 0.0f);
        tj[t] = make_float4(x1, y1, x2, y2);
        ta[t] = cw * ch;
        float s = scores[j];
        unsigned int sb  = __float_as_uint(s);
        unsigned int asc = (sb & 0x80000000u) ? ~sb : (sb | 0x80000000u);
        unsigned int hi  = valid ? ~asc : 0xFFFFFFFFu;   // smaller key = better
        tk[t] = ((unsigned long long)hi << 32) | (unsigned int)j;
        if (bi == bj) {                                   // own rows: persist
            keys_g[j]   = tk[t];
            validb_g[j] = valid ? 1 : 0;
            cxcywh_g[j] = make_float4(0.5f * (x1 + x2), 0.5f * (y1 + y2), cw, ch);
        }
    }
    if (bj == 0) {                                        // zero-init chores
        if (t < 128) rank_g[ib + t] = 0;
        if (t < 4)   done_g[bi * 4 + t] = 0;
        if (t < 16) { int r = bi * 16 + t; if (r < npro) out[r] = make_float4(0.f, 0.f, 0.f, 0.f); }
    }
    __syncthreads();

    int r = t >> 1, l = t & 1;
    int i = ib + r;
    float4 bx = boxes[i];
    float hw = 0.5f * bx.z, hh = 0.5f * bx.w;
    float x1 = fminf(fmaxf(bx.x - hw, 0.0f), xmax);
    float x2 = fminf(fmaxf(bx.x + hw, 0.0f), xmax);
    float y1 = fminf(fmaxf(bx.y - hh, 0.0f), ymax);
    float y2 = fminf(fmaxf(bx.y + hh, 0.0f), ymax);
    float ai = (x2 - x1) * (y2 - y1);
    float s = scores[i];
    unsigned int sb  = __float_as_uint(s);
    unsigned int asc = (sb & 0x80000000u) ? ~sb : (sb | 0x80000000u);
    bool vi = ((x2 - x1) > 0.0f) && ((y2 - y1) > 0.0f);
    unsigned int hi = vi ? ~asc : 0xFFFFFFFFu;
    unsigned long long ki = ((unsigned long long)hi << 32) | (unsigned int)i;

    for (int jj = l; jj < 128; jj += 2) {
        int j = jb + jj;
        if (j >= i) break;                 // lower triangle by index
        float4 bj4 = tj[jj];
        float ix1 = fmaxf(x1, bj4.x);
        float iy1 = fmaxf(y1, bj4.y);
        float ix2 = fminf(x2, bj4.z);
        float iy2 = fminf(y2, bj4.w);
        float iw  = fmaxf(ix2 - ix1, 0.0f);
        float ih  = fmaxf(iy2 - iy1, 0.0f);
        float inter = iw * ih;
        float uni   = ai + ta[jj] - inter;
        float iou   = inter / fmaxf(uni, 1e-8f);
        if (iou > 0.7f) {
            unsigned long long kj = tk[jj];
            unsigned int loser, winner;
            if (ki < kj) { winner = (unsigned int)i; loser = (unsigned int)j; }
            else         { winner = (unsigned int)j; loser = (unsigned int)i; }
            int pos = atomicAdd(counter, 1);
            if (pos < ecap) edges[pos] = (loser << 16) | winner;
        }
    }
}

// -------------------------------------------------------------- resolve -----
// Bitmask fixpoint of kept[l] = valid[l] && !any(kept[w] : edge (l,w));
// unique solution (edges follow strict key order => well-founded DAG).
// Emits kept bytes and rkeys[i] = kept ? key : ~0.
__global__ __launch_bounds__(1024)
void resolve_kernel(const unsigned char* __restrict__ validg,
                    const unsigned int* __restrict__ edges,
                    const int* __restrict__ counter,
                    const unsigned long long* __restrict__ keys,
                    unsigned char* __restrict__ keptg,
                    unsigned long long* __restrict__ rkeys, int ecap) {
    __shared__ unsigned int keptw[256];
    __shared__ unsigned int validw[256];
    __shared__ unsigned int sup[256];
    __shared__ int s_changed;
    int t = threadIdx.x;
    int E = *counter;
    if (E > ecap) E = ecap;
    int wv = t >> 6, lane = t & 63;
    for (int g = wv; g < 128; g += 16) {
        unsigned long long m = __ballot(validg[g * 64 + lane] != 0);
        if (lane == 0) {
            validw[2 * g]     = (unsigned int)m;
            validw[2 * g + 1] = (unsigned int)(m >> 32);
        }
    }
    __syncthreads();
    if (t < 256) keptw[t] = validw[t];
    __syncthreads();
    for (int iter = 0; iter < NBOX; ++iter) {
        if (t < 256) sup[t] = 0u;
        if (t == 0) s_changed = 0;
        __syncthreads();
        for (int e = t; e < E; e += 1024) {
            unsigned int ed = edges[e];
            unsigned int l = ed >> 16, w = ed & 0xFFFFu;
            if ((keptw[w >> 5] >> (w & 31)) & 1u)
                atomicOr(&sup[l >> 5], 1u << (l & 31));
        }
        __syncthreads();
        if (t < 256) {
            unsigned int nk = validw[t] & ~sup[t];
            if (nk != keptw[t]) { keptw[t] = nk; s_changed = 1; }
        }
        __syncthreads();
        int done = (s_changed == 0);
        __syncthreads();
        if (done) break;
    }
    for (int i = t; i < NBOX; i += 1024) {
        unsigned int k = (keptw[i >> 5] >> (i & 31)) & 1u;
        keptg[i] = (unsigned char)k;
        rkeys[i] = k ? keys[i] : ~0ull;
    }
}

// ------------------------------------------------- rank + fused scatter -----
// rank[i] = #{ j : kept[j] && key[j] < key[i] } accumulated over 8 j-chunks
// by 2048 blocks (chunk = bid>>8, rowgroup = bid&255; 32 rows x 8 lanes).
// Last block per rowgroup (done[] counter) scatters: kept && rank<npro ->
// out[rank] = cxcywh. Keys unique => ranks unique/dense => exact top_k order.
#define RCHUNK 1024
__global__ __launch_bounds__(256)
void rank_scatter_kernel(const unsigned long long* __restrict__ keys,
                         const unsigned long long* __restrict__ rkeys,
                         const unsigned char* __restrict__ keptg,
                         const float4* __restrict__ cxcywh,
                         int* __restrict__ rank, int* __restrict__ done,
                         float4* __restrict__ out, int npro) {
    __shared__ unsigned long long tkl[RCHUNK];
    __shared__ int s_last;
    int t = threadIdx.x;
    int chunk = blockIdx.x >> 8;
    int rowg  = blockIdx.x & 255;
    int jbase = chunk * RCHUNK;
#pragma unroll
    for (int m = 0; m < RCHUNK / 256; ++m) tkl[t + m * 256] = rkeys[jbase + t + m * 256];
    __syncthreads();
    int row = rowg * 32 + (t >> 3);
    int lane = t & 7;
    unsigned long long ki = keys[row];
    int partial = 0;
#pragma unroll 16
    for (int j = lane; j < RCHUNK; j += 8) partial += (tkl[j] < ki) ? 1 : 0;
    partial += __shfl_down(partial, 4, 8);
    partial += __shfl_down(partial, 2, 8);
    partial += __shfl_down(partial, 1, 8);
    if (lane == 0 && partial) atomicAdd(&rank[row], partial);
    __syncthreads();
    if (t == 0) {
        __threadfence();
        int old = atomicAdd(&done[rowg], 1);
        s_last = (old == 7) ? 1 : 0;
    }
    __syncthreads();
    if (s_last && t < 32) {
        int r2 = rowg * 32 + t;
        if (keptg[r2]) {
            int rk = atomicAdd(&rank[r2], 0);      // atomic read (L1-bypass)
            if (rk < npro) out[rk] = cxcywh[r2];
        }
    }
}

// --------------------------------------------------------------- host -------
extern "C" void kernel_launch(void* const* d_in, const int* in_sizes, int n_in,
                              void* d_out, int out_size, void* d_ws, size_t ws_size,
                              hipStream_t stream) {
    const float4* boxes  = (const float4*)d_in[0];
    const float* scores  = (const float*)d_in[1];
    const int* ph        = (const int*)d_in[2];
    const int* pw        = (const int*)d_in[3];

    char* ws = (char*)d_ws;
    size_t off = 0;
    unsigned long long* keys  = (unsigned long long*)(ws + off); off += (size_t)NBOX * 8;
    unsigned long long* rkeys = (unsigned long long*)(ws + off); off += (size_t)NBOX * 8;
    float4* cxcywh = (float4*)(ws + off); off += (size_t)NBOX * 16;
    int* rank      = (int*)(ws + off);    off += (size_t)NBOX * 4;
    int* done      = (int*)(ws + off);    off += 256 * 4;
    unsigned char* validb = (unsigned char*)(ws + off); off += NBOX;
    unsigned char* keptg  = (unsigned char*)(ws + off); off += NBOX;
    off = (off + 63) & ~(size_t)63;
    int* counter = (int*)(ws + off); off += 64;
    unsigned int* edges = (unsigned int*)(ws + off);

    int ecap = 262144;
    if (ws_size > off) {
        size_t room = (ws_size - off) / 4;
        if ((size_t)ecap > room) ecap = (int)room;
    } else {
        ecap = 0;
    }
    int npro = out_size / 4;

    hipMemsetAsync(counter, 0, 64, stream);
    int ntiles = NBOX / 128;                                   // 64
    edge_kernel<<<ntiles * (ntiles + 1) / 2, 256, 0, stream>>>(
        boxes, scores, ph, pw, keys, validb, cxcywh,
        (float4*)d_out, npro, rank, done, edges, counter, ecap);
    resolve_kernel<<<1, 1024, 0, stream>>>(validb, edges, counter, keys, keptg,
                                           rkeys, ecap);
    rank_scatter_kernel<<<(NBOX / 32) * (NBOX / RCHUNK), 256, 0, stream>>>(
        keys, rkeys, keptg, cxcywh, rank, done, (float4*)d_out, npro);
}